// Round 1
// baseline (591.095 us; speedup 1.0000x reference)
//
#include <hip/hip_runtime.h>
#include <math.h>

// TreeLSTM on 32 complete binary trees, depth 10, heap order. d=128.
// Structure hard-coded from the reference _build_forest():
//   tree t occupies nodes [t*2047, (t+1)*2047); node j's children: 2j+1, 2j+2
//   internal nodes: j in [0,1023); leaves: j in [1023, 2047)
//   level n processes tree-depth (10-n); leaves level 0, root level 10.
// wx_f is identical for both edges of a parent -> computed per internal node.

#define D128 128
#define NTREES 32
#define MTREE 2047
#define INT_TREE 1023
#define NNODES (NTREES * MTREE)   // 65504
#define NINT   (NTREES * INT_TREE) // 32736

__device__ __forceinline__ float sigmoidf_(float x) {
    return 1.0f / (1.0f + __expf(-x));
}
__device__ __forceinline__ float tanhf_(float x) {
    x = fminf(fmaxf(x, -10.0f), 10.0f);
    float e = __expf(2.0f * x);
    return (e - 1.0f) / (e + 1.0f);
}

// idx: level-local node index (0..32*2^dep), dep = tree depth of this level.
__device__ __forceinline__ void node_ids(int idx, int dep, int& v, int& lc, int& rf) {
    int tree = idx >> dep;
    int pos  = idx - (tree << dep);
    int j    = ((1 << dep) - 1) + pos;   // tree-local heap index
    v  = tree * MTREE + j;
    lc = v + j + 1;                      // tree*2047 + 2j+1 (left child; right = lc+1)
    rf = tree * INT_TREE + j;            // compact internal-row index for wx_f
}

// ---------------------------------------------------------------------------
// C[M x Nc] = gatherRows(A)[M x 128] * B[128 x Nc] + bias[Nc]
// GATHER=1: row m -> global row m + 1024*(m/1023)  (internal-node gather)
// block 256, tile 64x64, K=128 resident in LDS, 4x4 microtile.
template<int GATHER>
__global__ __launch_bounds__(256) void gemm_k(const float* __restrict__ A,
                                              const float* __restrict__ B,
                                              const float* __restrict__ bias,
                                              float* __restrict__ C,
                                              int M, int Nc) {
    __shared__ float As[128 * 68];   // As[k][m], stride 68 (16B-aligned float4 rows)
    __shared__ float Bs[128 * 64];   // Bs[k][n]
    const int tid = threadIdx.x;
    const int m0 = blockIdx.x * 64;
    const int n0 = blockIdx.y * 64;

#pragma unroll
    for (int r = 0; r < 32; ++r) {
        int fi  = tid + 256 * r;      // 0..8191
        int k   = fi & 127;
        int row = fi >> 7;
        int gm  = m0 + row; gm = (gm < M) ? gm : (M - 1);
        int grow = gm;
        if (GATHER) { int t = gm / 1023; grow = gm + 1024 * t; }
        As[k * 68 + row] = A[(size_t)grow * 128 + k];
    }
#pragma unroll
    for (int r = 0; r < 32; ++r) {
        int fi = tid + 256 * r;
        int n  = fi & 63;
        int k  = fi >> 6;
        Bs[k * 64 + n] = B[(size_t)k * Nc + n0 + n];
    }
    __syncthreads();

    const int tm = (tid & 15) * 4;
    const int tn = (tid >> 4) * 4;
    float acc[4][4] = {};
#pragma unroll 4
    for (int k = 0; k < 128; ++k) {
        float4 a = *(const float4*)&As[k * 68 + tm];
        float4 b = *(const float4*)&Bs[k * 64 + tn];
        float av[4] = {a.x, a.y, a.z, a.w};
        float bv[4] = {b.x, b.y, b.z, b.w};
#pragma unroll
        for (int i = 0; i < 4; ++i)
#pragma unroll
            for (int j = 0; j < 4; ++j)
                acc[i][j] += av[i] * bv[j];
    }
    float4 bb = *(const float4*)&bias[n0 + tn];
    float bvv[4] = {bb.x, bb.y, bb.z, bb.w};
#pragma unroll
    for (int i = 0; i < 4; ++i) {
        int gm = m0 + tm + i;
        if (gm < M) {
            float4 o = {acc[i][0] + bvv[0], acc[i][1] + bvv[1],
                        acc[i][2] + bvv[2], acc[i][3] + bvv[3]};
            *(float4*)&C[(size_t)gm * Nc + n0 + tn] = o;
        }
    }
}

// ---------------------------------------------------------------------------
// Leaves (level 0): c = sig(i)*tanh(u); h = sig(o)*tanh(c). One thread/element.
__global__ __launch_bounds__(256) void leaves_k(const float* __restrict__ wx_iou,
                                                float* __restrict__ h,
                                                float* __restrict__ c) {
    int e = blockIdx.x * 256 + threadIdx.x;   // 32768 leaves * 128
    int leaf = e >> 7, cc = e & 127;
    int tree = leaf >> 10, pos = leaf & 1023;
    int v = tree * MTREE + INT_TREE + pos;
    const float* wr = &wx_iou[(size_t)v * 384];
    float iv = sigmoidf_(wr[cc]);
    float ov = sigmoidf_(wr[128 + cc]);
    float uv = tanhf_(wr[256 + cc]);
    float cn = iv * uv;
    c[(size_t)v * 128 + cc] = cn;
    h[(size_t)v * 128 + cc] = ov * tanhf_(cn);
}

// ---------------------------------------------------------------------------
// One level (dep = 10-n). NB=8 parent nodes per block, 128 threads.
__global__ __launch_bounds__(128) void level_k(const float* __restrict__ wx_iou,
                                               const float* __restrict__ wx_f,
                                               const float* __restrict__ U_iou,
                                               const float* __restrict__ U_f,
                                               float* __restrict__ h,
                                               float* __restrict__ c,
                                               int dep) {
    const int NB = 8;
    __shared__ float s_h[NB * 256];    // children h: [nb*256+0..127]=left, [128..255]=right
    __shared__ float s_hs[NB * 128];   // h_sum
    __shared__ float s_act[NB * 384];  // activated i,o,u
    __shared__ float s_f[NB * 256];    // activated fl (0..127), fr (128..255)
    const int tid = threadIdx.x;
    const int idx0 = blockIdx.x * NB;

    // stage children h (two contiguous rows per node)
#pragma unroll
    for (int r = 0; r < 4; ++r) {
        int fi = tid + 128 * r;        // 0..511 float4s
        int nb = fi >> 6;
        int off = (fi & 63) * 4;
        int v_, lc_, rf_; node_ids(idx0 + nb, dep, v_, lc_, rf_);
        float4 t = *(const float4*)&h[((size_t)lc_ << 7) + off];
        *(float4*)&s_h[nb * 256 + off] = t;
    }
    __syncthreads();
#pragma unroll
    for (int r = 0; r < 2; ++r) {
        int fi = tid + 128 * r;        // 0..255 float4s
        int nb = fi >> 5;
        int off = (fi & 31) * 4;
        float4 a = *(const float4*)&s_h[nb * 256 + off];
        float4 b = *(const float4*)&s_h[nb * 256 + 128 + off];
        float4 s = {a.x + b.x, a.y + b.y, a.z + b.z, a.w + b.w};
        *(float4*)&s_hs[nb * 128 + off] = s;
    }
    __syncthreads();

    // ---- f phase: wave0 = fl, wave1 = fr; each thread 2 columns, 8 nodes ----
    {
        const int side = tid >> 6;     // wave-uniform
        const int col  = tid & 63;
        float acc0[NB] = {}; float acc1[NB] = {};
        for (int k4 = 0; k4 < 128; k4 += 4) {
            float u00 = U_f[(k4 + 0) * 128 + col], u01 = U_f[(k4 + 0) * 128 + col + 64];
            float u10 = U_f[(k4 + 1) * 128 + col], u11 = U_f[(k4 + 1) * 128 + col + 64];
            float u20 = U_f[(k4 + 2) * 128 + col], u21 = U_f[(k4 + 2) * 128 + col + 64];
            float u30 = U_f[(k4 + 3) * 128 + col], u31 = U_f[(k4 + 3) * 128 + col + 64];
#pragma unroll
            for (int nb = 0; nb < NB; ++nb) {
                float4 hv = *(const float4*)&s_h[nb * 256 + side * 128 + k4];
                acc0[nb] += hv.x * u00 + hv.y * u10 + hv.z * u20 + hv.w * u30;
                acc1[nb] += hv.x * u01 + hv.y * u11 + hv.z * u21 + hv.w * u31;
            }
        }
#pragma unroll
        for (int nb = 0; nb < NB; ++nb) {
            int v_, lc_, rf_; node_ids(idx0 + nb, dep, v_, lc_, rf_);
            float w0 = wx_f[(size_t)rf_ * 128 + col];
            float w1 = wx_f[(size_t)rf_ * 128 + col + 64];
            s_f[nb * 256 + side * 128 + col]      = sigmoidf_(acc0[nb] + w0);
            s_f[nb * 256 + side * 128 + col + 64] = sigmoidf_(acc1[nb] + w1);
        }
    }

    // ---- iou phase: thread owns cols tid (i), tid+128 (o), tid+256 (u) ----
    {
        float a0[NB] = {}, a1[NB] = {}, a2[NB] = {};
        for (int k4 = 0; k4 < 128; k4 += 4) {
            float u0[4], u1[4], u2[4];
#pragma unroll
            for (int i = 0; i < 4; ++i) {
                const float* ur = &U_iou[(k4 + i) * 384 + tid];
                u0[i] = ur[0]; u1[i] = ur[128]; u2[i] = ur[256];
            }
#pragma unroll
            for (int nb = 0; nb < NB; ++nb) {
                float4 hv = *(const float4*)&s_hs[nb * 128 + k4];
                a0[nb] += hv.x * u0[0] + hv.y * u0[1] + hv.z * u0[2] + hv.w * u0[3];
                a1[nb] += hv.x * u1[0] + hv.y * u1[1] + hv.z * u1[2] + hv.w * u1[3];
                a2[nb] += hv.x * u2[0] + hv.y * u2[1] + hv.z * u2[2] + hv.w * u2[3];
            }
        }
#pragma unroll
        for (int nb = 0; nb < NB; ++nb) {
            int v_, lc_, rf_; node_ids(idx0 + nb, dep, v_, lc_, rf_);
            const float* wr = &wx_iou[(size_t)v_ * 384];
            s_act[nb * 384 + tid]       = sigmoidf_(a0[nb] + wr[tid]);
            s_act[nb * 384 + 128 + tid] = sigmoidf_(a1[nb] + wr[tid + 128]);
            s_act[nb * 384 + 256 + tid] = tanhf_(a2[nb] + wr[tid + 256]);
        }
    }
    __syncthreads();

    // ---- epilogue: c_new = i*u + fl*cl + fr*cr; h = o*tanh(c_new) ----
#pragma unroll
    for (int r = 0; r < 8; ++r) {
        int fi = tid + 128 * r;        // 0..1023
        int nb = fi >> 7;
        int cc = fi & 127;
        int v_, lc_, rf_; node_ids(idx0 + nb, dep, v_, lc_, rf_);
        float iv = s_act[nb * 384 + cc];
        float ov = s_act[nb * 384 + 128 + cc];
        float uv = s_act[nb * 384 + 256 + cc];
        float fl = s_f[nb * 256 + cc];
        float fr = s_f[nb * 256 + 128 + cc];
        float cl = c[((size_t)lc_ << 7) + cc];
        float cr = c[((size_t)lc_ << 7) + 128 + cc];
        float cn = iv * uv + fl * cl + fr * cr;
        c[((size_t)v_ << 7) + cc] = cn;
        h[((size_t)v_ << 7) + cc] = ov * tanhf_(cn);
    }
}

// ---------------------------------------------------------------------------
extern "C" void kernel_launch(void* const* d_in, const int* in_sizes, int n_in,
                              void* d_out, int out_size, void* d_ws, size_t ws_size,
                              hipStream_t stream) {
    const float* features = (const float*)d_in[0];
    const float* W_iou    = (const float*)d_in[1];
    const float* b_iou    = (const float*)d_in[2];
    const float* U_iou    = (const float*)d_in[3];
    const float* W_f      = (const float*)d_in[4];
    const float* b_f      = (const float*)d_in[5];
    const float* U_f      = (const float*)d_in[6];
    float* h = (float*)d_out;

    // ws layout (floats): wx_iou [N*384] | wx_f [NINT*128] | c [N*128]  = ~151 MB
    float* ws = (float*)d_ws;
    float* wx_iou = ws;
    float* wx_f   = wx_iou + (size_t)NNODES * 384;
    float* c      = wx_f + (size_t)NINT * 128;

    // 1) wx_iou = F @ W_iou + b_iou
    hipLaunchKernelGGL((gemm_k<0>), dim3((NNODES + 63) / 64, 6), dim3(256), 0, stream,
                       features, W_iou, b_iou, wx_iou, NNODES, 384);
    // 2) wx_f (internal nodes only, compact rows) = F[internal] @ W_f + b_f
    hipLaunchKernelGGL((gemm_k<1>), dim3((NINT + 63) / 64, 2), dim3(256), 0, stream,
                       features, W_f, b_f, wx_f, NINT, 128);
    // 3) leaves
    hipLaunchKernelGGL(leaves_k, dim3((NTREES * 1024 * 128) / 256), dim3(256), 0, stream,
                       wx_iou, h, c);
    // 4) levels bottom-up: dep 9 .. 0
    for (int dep = 9; dep >= 0; --dep) {
        int P = 1 << dep;
        int blocks = (NTREES * P) / 8;   // NB=8 divides 32*P for all dep>=0
        hipLaunchKernelGGL(level_k, dim3(blocks), dim3(128), 0, stream,
                           wx_iou, wx_f, U_iou, U_f, h, c, dep);
    }
}

// Round 2
// 574.036 us; speedup vs baseline: 1.0297x; 1.0297x over previous
//
#include <hip/hip_runtime.h>
#include <math.h>
#include <stdint.h>

// TreeLSTM, 32 complete binary trees depth 10, heap order, d=128.
// R2: bf16 MFMA for the two big GEMMs and all level matvecs.
//   wx_iou / wx_f stored bf16 (error budget ok vs 1.94e-2 threshold).
//   Level kernel: 64 parents/block, children h staged bf16 in LDS,
//   U^T fragments read from global (L2-resident), f-gate pair-sum in-lane.

#define NTREES 32
#define MTREE 2047
#define INT_TREE 1023
#define NNODES (NTREES * MTREE)     // 65504
#define NINT   (NTREES * INT_TREE) // 32736

typedef __attribute__((ext_vector_type(8))) short bf16x8;
typedef __attribute__((ext_vector_type(4))) float f32x4;

__device__ __forceinline__ float sigmoidf_(float x) {
    return 1.0f / (1.0f + __expf(-x));
}
__device__ __forceinline__ float tanhf_(float x) {
    x = fminf(fmaxf(x, -10.0f), 10.0f);
    float e = __expf(2.0f * x);
    return (e - 1.0f) / (e + 1.0f);
}
__device__ __forceinline__ float bf2f(uint16_t b) {
    union { uint32_t u; float f; } v; v.u = ((uint32_t)b) << 16; return v.f;
}
__device__ __forceinline__ uint16_t f2bf(float f) {
    union { float f; uint32_t u; } v; v.f = f;
    uint32_t r = v.u + 0x7FFF + ((v.u >> 16) & 1);   // RNE
    return (uint16_t)(r >> 16);
}
__device__ __forceinline__ uint4 pack_bf8(float4 a, float4 b) {
    uint4 r;
    r.x = (uint32_t)f2bf(a.x) | ((uint32_t)f2bf(a.y) << 16);
    r.y = (uint32_t)f2bf(a.z) | ((uint32_t)f2bf(a.w) << 16);
    r.z = (uint32_t)f2bf(b.x) | ((uint32_t)f2bf(b.y) << 16);
    r.w = (uint32_t)f2bf(b.z) | ((uint32_t)f2bf(b.w) << 16);
    return r;
}
// bf16 elementwise add of two 8-wide frags (for h_sum = h_left + h_right)
__device__ __forceinline__ bf16x8 bfadd8(bf16x8 a, bf16x8 b) {
    bf16x8 r;
#pragma unroll
    for (int e = 0; e < 8; ++e)
        r[e] = (short)f2bf(bf2f((uint16_t)a[e]) + bf2f((uint16_t)b[e]));
    return r;
}

// idx: level-local node index; dep = tree depth of this level.
__device__ __forceinline__ void node_ids(int idx, int dep, int& v, int& lc, int& rf) {
    int tree = idx >> dep;
    int pos  = idx - (tree << dep);
    int j    = ((1 << dep) - 1) + pos;
    v  = tree * MTREE + j;
    lc = v + j + 1;              // left child; right = lc+1
    rf = tree * INT_TREE + j;    // compact internal row for wx_f
}

// ---------------------------------------------------------------------------
// Prep: transpose + cast the 4 weight matrices to bf16 row-major [n][k].
__global__ __launch_bounds__(128) void prep_k(const float* __restrict__ Wiou,
                                              const float* __restrict__ Wf,
                                              const float* __restrict__ Uiou,
                                              const float* __restrict__ Uf,
                                              uint16_t* __restrict__ WiouT,
                                              uint16_t* __restrict__ WfT,
                                              uint16_t* __restrict__ UiouT,
                                              uint16_t* __restrict__ UfT) {
    int n = blockIdx.x, k = threadIdx.x;
    if (n < 384)      WiouT[n * 128 + k] = f2bf(Wiou[k * 384 + n]);
    else if (n < 512) { int m = n - 384; WfT[m * 128 + k] = f2bf(Wf[k * 128 + m]); }
    else if (n < 896) { int m = n - 512; UiouT[m * 128 + k] = f2bf(Uiou[k * 384 + m]); }
    else              { int m = n - 896; UfT[m * 128 + k] = f2bf(Uf[k * 128 + m]); }
}

// ---------------------------------------------------------------------------
// C_bf16[M x Nc] = gatherRows(A_f32)[M x 128] @ BT_bf16^T + bias_f32
// Tile 64x64, K=128, 256 threads (4 waves, wave w = m-tile w).
// LDS layout: [row][k] bf16, 16B chunks XOR-swizzled by (row&7).
template<int GATHER>
__global__ __launch_bounds__(256, 4) void gemm_k(const float* __restrict__ A,
                                                 const uint16_t* __restrict__ BT,
                                                 const float* __restrict__ bias,
                                                 uint16_t* __restrict__ Cout,
                                                 int M, int Nc) {
    __shared__ uint16_t As[64 * 128];
    __shared__ uint16_t Bs[64 * 128];
    const int tid = threadIdx.x;
    const int m0 = blockIdx.x * 64, n0 = blockIdx.y * 64;

#pragma unroll
    for (int r = 0; r < 4; ++r) {              // A: 1024 16B chunks, f32 -> bf16
        int ci = r * 256 + tid;
        int row = ci >> 4, cx = ci & 15;
        int gm = m0 + row; gm = gm < M ? gm : M - 1;
        int grow = gm;
        if (GATHER) { int t = gm / 1023; grow = gm + 1024 * t; }
        const float* src = A + (size_t)grow * 128 + cx * 8;
        float4 f0 = *(const float4*)src;
        float4 f1 = *(const float4*)(src + 4);
        *(uint4*)&As[row * 128 + (cx ^ (row & 7)) * 8] = pack_bf8(f0, f1);
    }
#pragma unroll
    for (int r = 0; r < 4; ++r) {              // B^T rows: straight bf16 copy
        int ci = r * 256 + tid;
        int n = ci >> 4, cx = ci & 15;
        uint4 v = *(const uint4*)(BT + (size_t)(n0 + n) * 128 + cx * 8);
        *(uint4*)&Bs[n * 128 + (cx ^ (n & 7)) * 8] = v;
    }
    __syncthreads();

    const int w = tid >> 6, lane = tid & 63, q = lane >> 4, l15 = lane & 15;
    f32x4 acc[4] = {};
#pragma unroll
    for (int ks = 0; ks < 4; ++ks) {
        int ar = w * 16 + l15;
        bf16x8 af = *(const bf16x8*)&As[ar * 128 + ((ks * 4 + q) ^ (ar & 7)) * 8];
#pragma unroll
        for (int nt = 0; nt < 4; ++nt) {
            int br = nt * 16 + l15;
            bf16x8 bf = *(const bf16x8*)&Bs[br * 128 + ((ks * 4 + q) ^ (br & 7)) * 8];
            acc[nt] = __builtin_amdgcn_mfma_f32_16x16x32_bf16(af, bf, acc[nt], 0, 0, 0);
        }
    }
#pragma unroll
    for (int nt = 0; nt < 4; ++nt) {
        int col = n0 + nt * 16 + l15;
        float bv = bias[col];
#pragma unroll
        for (int reg = 0; reg < 4; ++reg) {
            int gm = m0 + w * 16 + q * 4 + reg;
            if (gm < M) Cout[(size_t)gm * Nc + col] = f2bf(acc[nt][reg] + bv);
        }
    }
}

// ---------------------------------------------------------------------------
// Leaves: c = sig(i)*tanh(u); h = sig(o)*tanh(c). 4 elements/thread.
__global__ __launch_bounds__(256) void leaves_k(const uint16_t* __restrict__ wx_iou,
                                                float* __restrict__ h,
                                                float* __restrict__ c) {
    int e4 = blockIdx.x * 256 + threadIdx.x;   // 1,048,576 quads
    int leaf = e4 >> 5, c4 = (e4 & 31) * 4;
    int tree = leaf >> 10, pos = leaf & 1023;
    int v = tree * MTREE + INT_TREE + pos;
    const uint16_t* wr = wx_iou + (size_t)v * 384;
    ushort4 wi = *(const ushort4*)(wr + c4);
    ushort4 wo = *(const ushort4*)(wr + 128 + c4);
    ushort4 wu = *(const ushort4*)(wr + 256 + c4);
    uint16_t ia[4] = {wi.x, wi.y, wi.z, wi.w};
    uint16_t oa[4] = {wo.x, wo.y, wo.z, wo.w};
    uint16_t ua[4] = {wu.x, wu.y, wu.z, wu.w};
    float cv[4], hv[4];
#pragma unroll
    for (int e = 0; e < 4; ++e) {
        float iv = sigmoidf_(bf2f(ia[e]));
        float ov = sigmoidf_(bf2f(oa[e]));
        float uv = tanhf_(bf2f(ua[e]));
        float cn = iv * uv;
        cv[e] = cn;
        hv[e] = ov * tanhf_(cn);
    }
    *(float4*)&c[(size_t)v * 128 + c4] = *(float4*)cv;
    *(float4*)&h[(size_t)v * 128 + c4] = *(float4*)hv;
}

// ---------------------------------------------------------------------------
// One level: 64 parents/block, 256 threads (4 waves).
// Phase 1: stage 128 child-h rows into LDS as bf16 (chunk-swizzled).
// Phase 2: f-GEMM (128x128 @ UfT), sigmoid*c, in-lane pair-sum -> PS LDS.
// Phase 3: iou-GEMM (64x384 @ UiouT) with on-the-fly h_sum A-frags.
// Phase 4: epilogue: gates, c_new = i*u + PS, h = o*tanh(c_new).
__global__ __launch_bounds__(256, 2) void level_k(const uint16_t* __restrict__ wx_iou,
                                                  const uint16_t* __restrict__ wx_f,
                                                  const uint16_t* __restrict__ UiouT,
                                                  const uint16_t* __restrict__ UfT,
                                                  float* __restrict__ h,
                                                  float* __restrict__ c,
                                                  int dep, int cnt) {
    __shared__ uint16_t Hc[128 * 128];  // 32 KB: child rows, bf16, swizzled
    __shared__ float PS[64 * 128];      // 32 KB: pairwise f*c sums per parent
    const int tid = threadIdx.x;
    const int idx0 = blockIdx.x * 64;
    const int w = tid >> 6, lane = tid & 63, q = lane >> 4, l15 = lane & 15;

    // ---- stage children h ----
#pragma unroll
    for (int r = 0; r < 8; ++r) {
        int ci = r * 256 + tid;            // 2048 chunks (128 rows x 16)
        int row = ci >> 4, cx = ci & 15;
        int pl = row >> 1, side = row & 1;
        int pg = idx0 + pl;
        uint4 val = make_uint4(0, 0, 0, 0);
        if (pg < cnt) {
            int v_, lc_, rf_; node_ids(pg, dep, v_, lc_, rf_);
            const float* src = h + (size_t)(lc_ + side) * 128 + cx * 8;
            float4 f0 = *(const float4*)src;
            float4 f1 = *(const float4*)(src + 4);
            val = pack_bf8(f0, f1);
        }
        *(uint4*)&Hc[row * 128 + (cx ^ (row & 7)) * 8] = val;
    }
    __syncthreads();

    // ---- f-GEMM: child m-tiles {2w, 2w+1}, all 128 cols ----
    f32x4 facc[2][8] = {};
#pragma unroll
    for (int ks = 0; ks < 4; ++ks) {
        int r0 = (2 * w) * 16 + l15, r1 = (2 * w + 1) * 16 + l15;
        bf16x8 a0 = *(const bf16x8*)&Hc[r0 * 128 + ((ks * 4 + q) ^ (r0 & 7)) * 8];
        bf16x8 a1 = *(const bf16x8*)&Hc[r1 * 128 + ((ks * 4 + q) ^ (r1 & 7)) * 8];
#pragma unroll
        for (int nt = 0; nt < 8; ++nt) {
            int n = nt * 16 + l15;
            bf16x8 b = *(const bf16x8*)(UfT + (size_t)n * 128 + ks * 32 + q * 8);
            facc[0][nt] = __builtin_amdgcn_mfma_f32_16x16x32_bf16(a0, b, facc[0][nt], 0, 0, 0);
            facc[1][nt] = __builtin_amdgcn_mfma_f32_16x16x32_bf16(a1, b, facc[1][nt], 0, 0, 0);
        }
    }
    // f epilogue: fc = sigmoid(wx_f + acc) * c_child; pair-sum into PS
#pragma unroll
    for (int mt = 0; mt < 2; ++mt) {
#pragma unroll
        for (int nt = 0; nt < 8; ++nt) {
            int cc = nt * 16 + l15;
            float fc[4];
#pragma unroll
            for (int reg = 0; reg < 4; ++reg) {
                int rloc = (2 * w + mt) * 16 + q * 4 + reg;
                int pl = rloc >> 1, side = rloc & 1;
                int pg = idx0 + pl;
                int pc = pg < cnt ? pg : cnt - 1;
                int v_, lc_, rf_; node_ids(pc, dep, v_, lc_, rf_);
                float wxf = bf2f(wx_f[(size_t)rf_ * 128 + cc]);
                float cch = c[(size_t)(lc_ + side) * 128 + cc];
                fc[reg] = sigmoidf_(facc[mt][nt][reg] + wxf) * cch;
            }
            int pbase = (2 * w + mt) * 8 + 2 * q;
            PS[(pbase + 0) * 128 + cc] = fc[0] + fc[1];
            PS[(pbase + 1) * 128 + cc] = fc[2] + fc[3];
        }
    }

    // ---- iou-GEMM: parent m-tile w, 24 n-tiles (i:0-7, o:8-15, u:16-23) ----
    f32x4 iacc[24] = {};
#pragma unroll
    for (int ks = 0; ks < 4; ++ks) {
        int r0 = 2 * (w * 16 + l15), r1 = r0 + 1;
        bf16x8 a0 = *(const bf16x8*)&Hc[r0 * 128 + ((ks * 4 + q) ^ (r0 & 7)) * 8];
        bf16x8 a1 = *(const bf16x8*)&Hc[r1 * 128 + ((ks * 4 + q) ^ (r1 & 7)) * 8];
        bf16x8 a = bfadd8(a0, a1);          // h_sum fragment
#pragma unroll
        for (int nt = 0; nt < 24; ++nt) {
            int n = nt * 16 + l15;
            bf16x8 b = *(const bf16x8*)(UiouT + (size_t)n * 128 + ks * 32 + q * 8);
            iacc[nt] = __builtin_amdgcn_mfma_f32_16x16x32_bf16(a, b, iacc[nt], 0, 0, 0);
        }
    }
    __syncthreads();   // PS complete before reads

    // ---- epilogue ----
#pragma unroll
    for (int nt = 0; nt < 8; ++nt) {
        int cc = nt * 16 + l15;
#pragma unroll
        for (int reg = 0; reg < 4; ++reg) {
            int pl = w * 16 + 4 * q + reg;
            int pg = idx0 + pl;
            bool valid = pg < cnt;
            int pc = valid ? pg : cnt - 1;
            int v_, lc_, rf_; node_ids(pc, dep, v_, lc_, rf_);
            float wxi = bf2f(wx_iou[(size_t)v_ * 384 + cc]);
            float wxo = bf2f(wx_iou[(size_t)v_ * 384 + 128 + cc]);
            float wxu = bf2f(wx_iou[(size_t)v_ * 384 + 256 + cc]);
            float iv = sigmoidf_(iacc[nt][reg] + wxi);
            float ov = sigmoidf_(iacc[nt + 8][reg] + wxo);
            float uv = tanhf_(iacc[nt + 16][reg] + wxu);
            float cn = iv * uv + PS[pl * 128 + cc];
            if (valid) {
                c[(size_t)v_ * 128 + cc] = cn;
                h[(size_t)v_ * 128 + cc] = ov * tanhf_(cn);
            }
        }
    }
}

// ---------------------------------------------------------------------------
extern "C" void kernel_launch(void* const* d_in, const int* in_sizes, int n_in,
                              void* d_out, int out_size, void* d_ws, size_t ws_size,
                              hipStream_t stream) {
    const float* features = (const float*)d_in[0];
    const float* W_iou    = (const float*)d_in[1];
    const float* b_iou    = (const float*)d_in[2];
    const float* U_iou    = (const float*)d_in[3];
    const float* W_f      = (const float*)d_in[4];
    const float* b_f      = (const float*)d_in[5];
    const float* U_f      = (const float*)d_in[6];
    float* h = (float*)d_out;

    // ws: wx_iou bf16 | wx_f bf16 | c f32 | WiouT | WfT | UiouT | UfT  (~92.5 MB)
    char* wp = (char*)d_ws;
    uint16_t* wx_iou = (uint16_t*)wp; wp += (size_t)NNODES * 384 * 2;
    uint16_t* wx_f   = (uint16_t*)wp; wp += (size_t)NINT * 128 * 2;
    float*    c      = (float*)wp;    wp += (size_t)NNODES * 128 * 4;
    uint16_t* WiouT  = (uint16_t*)wp; wp += 384 * 128 * 2;
    uint16_t* WfT    = (uint16_t*)wp; wp += 128 * 128 * 2;
    uint16_t* UiouT  = (uint16_t*)wp; wp += 384 * 128 * 2;
    uint16_t* UfT    = (uint16_t*)wp; wp += 128 * 128 * 2;

    hipLaunchKernelGGL(prep_k, dim3(1024), dim3(128), 0, stream,
                       W_iou, W_f, U_iou, U_f, WiouT, WfT, UiouT, UfT);
    hipLaunchKernelGGL((gemm_k<0>), dim3(1024, 6), dim3(256), 0, stream,
                       features, WiouT, b_iou, wx_iou, NNODES, 384);
    hipLaunchKernelGGL((gemm_k<1>), dim3(512, 2), dim3(256), 0, stream,
                       features, WfT, b_f, wx_f, NINT, 128);
    hipLaunchKernelGGL(leaves_k, dim3(4096), dim3(256), 0, stream,
                       wx_iou, h, c);
    for (int dep = 9; dep >= 0; --dep) {
        int cnt = NTREES << dep;
        int blocks = (cnt + 63) / 64;
        hipLaunchKernelGGL(level_k, dim3(blocks), dim3(256), 0, stream,
                           wx_iou, wx_f, UiouT, UfT, h, c, dep, cnt);
    }
}

// Round 3
// 228.560 us; speedup vs baseline: 2.5862x; 2.5115x over previous
//
#include <hip/hip_runtime.h>
#include <math.h>
#include <stdint.h>

// TreeLSTM, 32 complete binary trees depth 10, heap order, d=128.
// R3: register-resident U b-frags (the R2 killer was per-MFMA global U loads),
//     i/o/u/f of the same columns owned by the same wave (lane-local combine),
//     transposed GEMM fused with leaf epilogue, per-tree tail kernel for dep6..0.

#define NTREES 32
#define MTREE 2047
#define NNODES (NTREES * MTREE)   // 65504

typedef __attribute__((ext_vector_type(8))) short bf16x8;
typedef __attribute__((ext_vector_type(4))) float f32x4;

__device__ __forceinline__ float sigmoidf_(float x) {
    return 1.0f / (1.0f + __expf(-x));
}
__device__ __forceinline__ float tanhf_(float x) {
    x = fminf(fmaxf(x, -10.0f), 10.0f);
    float e = __expf(2.0f * x);
    return (e - 1.0f) / (e + 1.0f);
}
__device__ __forceinline__ float bf2f(uint16_t b) {
    union { uint32_t u; float f; } v; v.u = ((uint32_t)b) << 16; return v.f;
}
__device__ __forceinline__ uint16_t f2bf(float f) {
    union { float f; uint32_t u; } v; v.f = f;
    uint32_t r = v.u + 0x7FFF + ((v.u >> 16) & 1);   // RNE
    return (uint16_t)(r >> 16);
}
__device__ __forceinline__ uint4 pack_bf8(float4 a, float4 b) {
    uint4 r;
    r.x = (uint32_t)f2bf(a.x) | ((uint32_t)f2bf(a.y) << 16);
    r.y = (uint32_t)f2bf(a.z) | ((uint32_t)f2bf(a.w) << 16);
    r.z = (uint32_t)f2bf(b.x) | ((uint32_t)f2bf(b.y) << 16);
    r.w = (uint32_t)f2bf(b.z) | ((uint32_t)f2bf(b.w) << 16);
    return r;
}

// Swizzled LDS layout for bf16 rows of 128 (16 chunks of 16B), XOR by row&7:
// conflict-free wave64 ds_read_b128 (2-way aliasing is free per m136).
#define SWZ(row, chunk) ((row) * 128 + (((chunk) ^ ((row) & 7)) * 8))

// ---------------------------------------------------------------------------
// Prep: WT[512][128] = [W_iou^T ; W_f^T] bf16, UT likewise, biasS = [b_iou;b_f].
__global__ __launch_bounds__(128) void prep_k(const float* __restrict__ Wiou,
                                              const float* __restrict__ Wf,
                                              const float* __restrict__ Uiou,
                                              const float* __restrict__ Uf,
                                              const float* __restrict__ biou,
                                              const float* __restrict__ bf,
                                              uint16_t* __restrict__ WT,
                                              uint16_t* __restrict__ UT,
                                              float* __restrict__ biasS) {
    int n = blockIdx.x, k = threadIdx.x;
    if (n < 512) {
        WT[n * 128 + k] = f2bf(n < 384 ? Wiou[k * 384 + n] : Wf[k * 128 + (n - 384)]);
    } else if (n < 1024) {
        int m = n - 512;
        UT[m * 128 + k] = f2bf(m < 384 ? Uiou[k * 384 + m] : Uf[k * 128 + (m - 384)]);
    } else {
#pragma unroll
        for (int r = 0; r < 4; ++r) {
            int j = r * 128 + k;
            biasS[j] = j < 384 ? biou[j] : bf[j - 384];
        }
    }
}

// ---------------------------------------------------------------------------
// Fused GEMM + leaf epilogue. Computes pre-acts for all 512 ucols of a
// 64-node group; leaf nodes -> h,c directly (no wx store); internal -> wx bf16.
// Wave w owns ucol-tiles {w, w+8, w+16, w+24} => i/o/u/f of cols w*16..w*16+15
// in the same lane across acc slots.
__global__ __launch_bounds__(512, 2) void gemm_leaf_k(const float* __restrict__ F,
                                                      const uint16_t* __restrict__ WT,
                                                      const float* __restrict__ biasS,
                                                      uint16_t* __restrict__ wx,
                                                      float* __restrict__ h,
                                                      float* __restrict__ c) {
    __shared__ uint16_t Fs[64 * 128];   // 16 KB
    const int tid = threadIdx.x;
    const int w = tid >> 6, lane = tid & 63, q = lane >> 4, l15 = lane & 15;
    const int n0 = blockIdx.x * 64;

    // stage 64 feature rows f32 -> bf16 swizzled
#pragma unroll
    for (int r = 0; r < 2; ++r) {
        int ci = r * 512 + tid;
        int row = ci >> 4, cx = ci & 15;
        int v = n0 + row; v = v < NNODES ? v : NNODES - 1;
        const float* src = F + (size_t)v * 128 + cx * 8;
        float4 f0 = *(const float4*)src;
        float4 f1 = *(const float4*)(src + 4);
        *(uint4*)&Fs[SWZ(row, cx)] = pack_bf8(f0, f1);
    }

    // resident A-frags (WT rows) + bias
    bf16x8 aW[4][4];
    float4 bias4[4];
#pragma unroll
    for (int s = 0; s < 4; ++s) {
        int row = (w + s * 8) * 16 + l15;
#pragma unroll
        for (int kc = 0; kc < 4; ++kc)
            aW[s][kc] = *(const bf16x8*)(WT + (size_t)row * 128 + kc * 32 + q * 8);
        bias4[s] = *(const float4*)(biasS + (w + s * 8) * 16 + q * 4);
    }
    __syncthreads();

#pragma unroll
    for (int nt = 0; nt < 4; ++nt) {
        bf16x8 b[4];
#pragma unroll
        for (int kc = 0; kc < 4; ++kc)
            b[kc] = *(const bf16x8*)&Fs[SWZ(nt * 16 + l15, kc * 4 + q)];
        f32x4 acc[4] = {};
#pragma unroll
        for (int s = 0; s < 4; ++s)
#pragma unroll
            for (int kc = 0; kc < 4; ++kc)
                acc[s] = __builtin_amdgcn_mfma_f32_16x16x32_bf16(aW[s][kc], b[kc], acc[s], 0, 0, 0);

        // epilogue: D(row=ucol q*4+r, col=node l15)
        int node = n0 + nt * 16 + l15;
        bool nvalid = node < NNODES;
        int v = nvalid ? node : NNODES - 1;
        int tree = v / 2047;
        int j = v - tree * 2047;
        bool leaf = j >= 1023;
        float pi[4], po[4], pu[4], pf[4];
#pragma unroll
        for (int r = 0; r < 4; ++r) {
            pi[r] = acc[0][r] + bias4[0][r];
            po[r] = acc[1][r] + bias4[1][r];
            pu[r] = acc[2][r] + bias4[2][r];
            pf[r] = acc[3][r] + bias4[3][r];
        }
        int colb = w * 16 + q * 4;
        if (nvalid && leaf) {
            float cv[4], hv[4];
#pragma unroll
            for (int r = 0; r < 4; ++r) {
                float iv = sigmoidf_(pi[r]);
                float ov = sigmoidf_(po[r]);
                float uv = tanhf_(pu[r]);
                float cn = iv * uv;
                cv[r] = cn;
                hv[r] = ov * tanhf_(cn);
            }
            *(float4*)&c[(size_t)v * 128 + colb] = *(float4*)cv;
            *(float4*)&h[(size_t)v * 128 + colb] = *(float4*)hv;
        }
        if (nvalid && !leaf) {
            ushort4 s0, s1, s2, s3;
            s0 = make_ushort4(f2bf(pi[0]), f2bf(pi[1]), f2bf(pi[2]), f2bf(pi[3]));
            s1 = make_ushort4(f2bf(po[0]), f2bf(po[1]), f2bf(po[2]), f2bf(po[3]));
            s2 = make_ushort4(f2bf(pu[0]), f2bf(pu[1]), f2bf(pu[2]), f2bf(pu[3]));
            s3 = make_ushort4(f2bf(pf[0]), f2bf(pf[1]), f2bf(pf[2]), f2bf(pf[3]));
            uint16_t* wr = wx + (size_t)v * 512 + colb;
            *(ushort4*)(wr)       = s0;
            *(ushort4*)(wr + 128) = s1;
            *(ushort4*)(wr + 256) = s2;
            *(ushort4*)(wr + 384) = s3;
        }
    }
}

// ---------------------------------------------------------------------------
// Climb core: one group of P<=32 parents (children contiguous from vc).
// bU: resident U^T b-frags (slot 0..2 = i/o/u cols w*16.., slot 3 = f cols).
__device__ __forceinline__ void climb_group(const uint16_t* __restrict__ wx,
                                            float* __restrict__ h,
                                            float* __restrict__ c,
                                            uint16_t* Hc, uint16_t* HS, float* PS,
                                            const bf16x8 bU[4][4],
                                            int vp, int vc, int P) {
    const int tid = threadIdx.x;
    const int w = tid >> 6, lane = tid & 63, q = lane >> 4, l15 = lane & 15;

    // ---- stage: Hc (64 child rows) + HS (32 pair-sum rows), bf16 swizzled ----
#pragma unroll
    for (int t = 0; t < 3; ++t) {
        int ci = t * 512 + tid;
        if (ci < 1024) {
            int row = ci >> 4, cx = ci & 15;
            uint4 val = make_uint4(0, 0, 0, 0);
            if (row < 2 * P) {
                const float* src = h + (size_t)(vc + row) * 128 + cx * 8;
                float4 f0 = *(const float4*)src;
                float4 f1 = *(const float4*)(src + 4);
                val = pack_bf8(f0, f1);
            }
            *(uint4*)&Hc[SWZ(row, cx)] = val;
        } else {
            int ci2 = ci - 1024;
            int prow = ci2 >> 4, cx = ci2 & 15;
            uint4 val = make_uint4(0, 0, 0, 0);
            if (prow < P) {
                const float* s0 = h + (size_t)(vc + 2 * prow) * 128 + cx * 8;
                const float* s1 = h + (size_t)(vc + 2 * prow + 1) * 128 + cx * 8;
                float4 a0 = *(const float4*)s0, a1 = *(const float4*)(s0 + 4);
                float4 b0 = *(const float4*)s1, b1 = *(const float4*)(s1 + 4);
                float4 u = {a0.x + b0.x, a0.y + b0.y, a0.z + b0.z, a0.w + b0.w};
                float4 v2 = {a1.x + b1.x, a1.y + b1.y, a1.z + b1.z, a1.w + b1.w};
                val = pack_bf8(u, v2);
            }
            *(uint4*)&HS[SWZ(prow, cx)] = val;
        }
    }
    __syncthreads();

    // ---- matvec: iou (A=HS) + f (A=Hc), B resident ----
    f32x4 accI[2][3] = {};
    f32x4 accF[4] = {};
#pragma unroll
    for (int mt = 0; mt < 2; ++mt) {
        bf16x8 a[4];
#pragma unroll
        for (int kc = 0; kc < 4; ++kc)
            a[kc] = *(const bf16x8*)&HS[SWZ(mt * 16 + l15, kc * 4 + q)];
#pragma unroll
        for (int s = 0; s < 3; ++s)
#pragma unroll
            for (int kc = 0; kc < 4; ++kc)
                accI[mt][s] = __builtin_amdgcn_mfma_f32_16x16x32_bf16(a[kc], bU[s][kc], accI[mt][s], 0, 0, 0);
    }
#pragma unroll
    for (int ct = 0; ct < 4; ++ct) {
        bf16x8 a[4];
#pragma unroll
        for (int kc = 0; kc < 4; ++kc)
            a[kc] = *(const bf16x8*)&Hc[SWZ(ct * 16 + l15, kc * 4 + q)];
#pragma unroll
        for (int kc = 0; kc < 4; ++kc)
            accF[ct] = __builtin_amdgcn_mfma_f32_16x16x32_bf16(a[kc], bU[3][kc], accF[ct], 0, 0, 0);
    }

    const int colf = w * 16 + l15;
    // ---- f epilogue: fc = sigmoid(acc + wx_f[parent]) * c_child; pair-sum ----
#pragma unroll
    for (int ct = 0; ct < 4; ++ct) {
        float fc[4];
#pragma unroll
        for (int r = 0; r < 4; ++r) {
            int cl = ct * 16 + q * 4 + r;        // child local index
            int pl = cl >> 1;
            float wxf = bf2f(wx[(size_t)(vp + pl) * 512 + 384 + colf]);
            float cch = c[(size_t)(vc + cl) * 128 + colf];
            fc[r] = sigmoidf_(accF[ct][r] + wxf) * cch;
        }
        PS[(ct * 8 + q * 2) * 128 + colf]     = fc[0] + fc[1];
        PS[(ct * 8 + q * 2 + 1) * 128 + colf] = fc[2] + fc[3];
    }
    __syncthreads();

    // ---- combine (lane-local i/o/u; PS via LDS) ----
#pragma unroll
    for (int mt = 0; mt < 2; ++mt) {
#pragma unroll
        for (int r = 0; r < 4; ++r) {
            int pl = mt * 16 + q * 4 + r;
            if (pl < P) {
                size_t vr = (size_t)(vp + pl);
                float wi = bf2f(wx[vr * 512 + colf]);
                float wo = bf2f(wx[vr * 512 + 128 + colf]);
                float wu = bf2f(wx[vr * 512 + 256 + colf]);
                float iv = sigmoidf_(accI[mt][0][r] + wi);
                float ov = sigmoidf_(accI[mt][1][r] + wo);
                float uv = tanhf_(accI[mt][2][r] + wu);
                float cn = iv * uv + PS[pl * 128 + colf];
                c[vr * 128 + colf] = cn;
                h[vr * 128 + colf] = ov * tanhf_(cn);
            }
        }
    }
}

__device__ __forceinline__ void load_bU(const uint16_t* __restrict__ UT, bf16x8 bU[4][4]) {
    const int tid = threadIdx.x;
    const int w = tid >> 6, lane = tid & 63, q = lane >> 4, l15 = lane & 15;
#pragma unroll
    for (int s = 0; s < 4; ++s) {
        int row = (w + s * 8) * 16 + l15;   // s=3 -> rows 384.. (f) since w+24
#pragma unroll
        for (int kc = 0; kc < 4; ++kc)
            bU[s][kc] = *(const bf16x8*)(UT + (size_t)row * 128 + kc * 32 + q * 8);
    }
}

// ---------------------------------------------------------------------------
// Big levels (dep >= 5): one 32-parent group per block.
__global__ __launch_bounds__(512, 2) void big_level_k(const uint16_t* __restrict__ wx,
                                                      const uint16_t* __restrict__ UT,
                                                      float* __restrict__ h,
                                                      float* __restrict__ c,
                                                      int dep) {
    __shared__ uint16_t Hc[64 * 128];   // 16 KB
    __shared__ uint16_t HS[32 * 128];   // 8 KB
    __shared__ float PS[32 * 128];      // 16 KB
    bf16x8 bU[4][4];
    load_bU(UT, bU);
    int idx0 = blockIdx.x * 32;             // level-local parent base
    int tree = idx0 >> dep;
    int pos0 = idx0 - (tree << dep);
    int vp = tree * MTREE + ((1 << dep) - 1) + pos0;
    int vc = tree * MTREE + ((2 << dep) - 1) + 2 * pos0;
    climb_group(wx, h, c, Hc, HS, PS, bU, vp, vc, 32);
}

// ---------------------------------------------------------------------------
// Tail: dep 6..0, one block per tree, __syncthreads between groups/levels.
__global__ __launch_bounds__(512, 2) void tail_k(const uint16_t* __restrict__ wx,
                                                 const uint16_t* __restrict__ UT,
                                                 float* __restrict__ h,
                                                 float* __restrict__ c) {
    __shared__ uint16_t Hc[64 * 128];
    __shared__ uint16_t HS[32 * 128];
    __shared__ float PS[32 * 128];
    bf16x8 bU[4][4];
    load_bU(UT, bU);
    const int tree = blockIdx.x;
    for (int dep = 6; dep >= 0; --dep) {
        int np = 1 << dep;
        for (int pos0 = 0; pos0 < np; pos0 += 32) {
            int P = np - pos0; P = P < 32 ? P : 32;
            int vp = tree * MTREE + (np - 1) + pos0;
            int vc = tree * MTREE + (2 * np - 1) + 2 * pos0;
            __syncthreads();   // LDS reuse + prev-level global writes visible
            climb_group(wx, h, c, Hc, HS, PS, bU, vp, vc, P);
        }
    }
}

// ---------------------------------------------------------------------------
extern "C" void kernel_launch(void* const* d_in, const int* in_sizes, int n_in,
                              void* d_out, int out_size, void* d_ws, size_t ws_size,
                              hipStream_t stream) {
    const float* features = (const float*)d_in[0];
    const float* W_iou    = (const float*)d_in[1];
    const float* b_iou    = (const float*)d_in[2];
    const float* U_iou    = (const float*)d_in[3];
    const float* W_f      = (const float*)d_in[4];
    const float* b_f      = (const float*)d_in[5];
    const float* U_f      = (const float*)d_in[6];
    float* h = (float*)d_out;

    // ws: wx bf16 [NNODES][512] | c f32 [NNODES][128] | WT | UT | biasS (~101 MB)
    char* wp = (char*)d_ws;
    uint16_t* wx    = (uint16_t*)wp; wp += (size_t)NNODES * 512 * 2;
    float*    c     = (float*)wp;    wp += (size_t)NNODES * 128 * 4;
    uint16_t* WT    = (uint16_t*)wp; wp += 512 * 128 * 2;
    uint16_t* UT    = (uint16_t*)wp; wp += 512 * 128 * 2;
    float*    biasS = (float*)wp;    wp += 512 * 4;

    hipLaunchKernelGGL(prep_k, dim3(1025), dim3(128), 0, stream,
                       W_iou, W_f, U_iou, U_f, b_iou, b_f, WT, UT, biasS);
    hipLaunchKernelGGL(gemm_leaf_k, dim3(1024), dim3(512), 0, stream,
                       features, WT, biasS, wx, h, c);
    hipLaunchKernelGGL(big_level_k, dim3(512), dim3(512), 0, stream, wx, UT, h, c, 9);
    hipLaunchKernelGGL(big_level_k, dim3(256), dim3(512), 0, stream, wx, UT, h, c, 8);
    hipLaunchKernelGGL(big_level_k, dim3(128), dim3(512), 0, stream, wx, UT, h, c, 7);
    hipLaunchKernelGGL(tail_k, dim3(32), dim3(512), 0, stream, wx, UT, h, c);
}